// Round 1
// baseline (1010.747 us; speedup 1.0000x reference)
//
#include <hip/hip_runtime.h>
#include <hip/hip_bf16.h>
#include <cstdint>
#include <cstddef>

// ---------------------------------------------------------------- constants
#define IN_CH   128
#define OUT_CH  64
#define CAT_CH  192   // IN_CH + OUT_CH

__device__ __forceinline__ void atomAddF(float* p, float v) {
    __hip_atomic_fetch_add(p, v, __ATOMIC_RELAXED, __HIP_MEMORY_SCOPE_AGENT);
}

// ---------------------------------------------------------------- dtype detect
// edge_index may be int64 (declared) or int32 (JAX x64 off). For int64 data of
// non-negative values < 2^31, every odd 32-bit word is zero. For int32 node ids
// (random in [0,50000)) odd words are essentially never all zero.
__global__ void detect_kernel(const unsigned int* __restrict__ ei, int* __restrict__ flag) {
    unsigned int v = ei[(threadIdx.x << 1) + 1];
    unsigned long long b = __ballot(v != 0u);
    if (threadIdx.x == 0) *flag = (b != 0ull) ? 1 : 0;   // 1 => int32 layout
}

__global__ void convert_kernel(const void* __restrict__ ei, int* __restrict__ row,
                               int* __restrict__ col, const int* __restrict__ flag, int E) {
    int i = blockIdx.x * blockDim.x + threadIdx.x;
    if (i >= E) return;
    if (*flag) {
        const int* p = (const int*)ei;
        row[i] = p[i];
        col[i] = p[E + i];
    } else {
        const long long* p = (const long long*)ei;
        row[i] = (int)p[i];
        col[i] = (int)p[E + i];
    }
}

// ---------------------------------------------------------------- degree / norm
__global__ void deg_init_kernel(float* __restrict__ deg, int n) {
    int i = blockIdx.x * blockDim.x + threadIdx.x;
    if (i < n) deg[i] = 1.0f;   // self-loop weight
}

__global__ void deg_add_kernel(const int* __restrict__ col, const float* __restrict__ w,
                               float* __restrict__ deg, int E) {
    int i = blockIdx.x * blockDim.x + threadIdx.x;
    if (i >= E) return;
    atomAddF(&deg[col[i]], w[i]);
}

__global__ void dinv_kernel(float* __restrict__ deg, int n) {
    int i = blockIdx.x * blockDim.x + threadIdx.x;
    if (i >= n) return;
    float d = deg[i];
    deg[i] = (d > 0.f) ? rsqrtf(d) : 0.f;
}

__global__ void norm_kernel(const int* __restrict__ row, const int* __restrict__ col,
                            const float* __restrict__ w, const float* __restrict__ dinv,
                            float* __restrict__ norm, int E) {
    int i = blockIdx.x * blockDim.x + threadIdx.x;
    if (i >= E) return;
    norm[i] = dinv[row[i]] * w[i] * dinv[col[i]];
}

// ---------------------------------------------------------------- weight pack
// Bzr[k*128 + c] = c<64 ? W_z[k][c] : W_r[k][c-64]   (k in [0,192))
__global__ void pack_bzr_kernel(const float* __restrict__ Wz, const float* __restrict__ Wr,
                                float* __restrict__ Bzr) {
    int i = blockIdx.x * blockDim.x + threadIdx.x;
    if (i >= CAT_CH * 128) return;
    int k = i >> 7, c = i & 127;
    Bzr[i] = (c < 64) ? Wz[k * 64 + c] : Wr[k * 64 + (c - 64)];
}

// ---------------------------------------------------------------- GEMM
// C(nrows x ldc, first TN cols) = [A0|A1](nrows x K) @ B(K x TN), fp32 vector.
// 256 threads, 64-row tile. Thread (tr,tc) owns 4 rows x CPT cols.
template <int K, int TN, bool ACC>
__global__ __launch_bounds__(256) void gemm_kernel(
    const float* __restrict__ A0, int a0w,
    const float* __restrict__ A1, int a1w,
    const float* __restrict__ B,
    float* __restrict__ C, int ldc, int nrows)
{
    __shared__ float As[16][64];
    __shared__ float Bs[16][TN];
    constexpr int CPT = TN / 16;

    const int t  = threadIdx.x;
    const int tr = t & 15;
    const int tc = t >> 4;
    const int rowBase = blockIdx.x * 64;

    float acc[4][CPT];
#pragma unroll
    for (int i = 0; i < 4; i++)
#pragma unroll
        for (int j = 0; j < CPT; j++) acc[i][j] = 0.f;

    const int ar  = t >> 2;   // 0..63 row in tile (A load)
    const int ac4 = t & 3;    // 0..3  k sub-chunk (A load)
    int arow = rowBase + ar;
    if (arow >= nrows) arow = nrows - 1;

    for (int k0 = 0; k0 < K; k0 += 16) {
        // stage A chunk (64 rows x 16 k), transposed into As[k][r]
        {
            int k = k0 + ac4 * 4;
            const float* src = (k < a0w) ? (A0 + (size_t)arow * a0w + k)
                                         : (A1 + (size_t)arow * a1w + (k - a0w));
            float4 v = *(const float4*)src;
            As[ac4 * 4 + 0][ar] = v.x;
            As[ac4 * 4 + 1][ar] = v.y;
            As[ac4 * 4 + 2][ar] = v.z;
            As[ac4 * 4 + 3][ar] = v.w;
        }
        // stage B chunk (16 k x TN)
        if (TN == 128) {
            int kk = t >> 4;
            int cb = (t & 15) * 8;
            const float* src = B + (size_t)(k0 + kk) * TN + cb;
            *(float4*)&Bs[kk][cb]     = *(const float4*)src;
            *(float4*)&Bs[kk][cb + 4] = *(const float4*)(src + 4);
        } else {  // TN == 64
            int kk = t >> 4;
            int cb = (t & 15) * 4;
            *(float4*)&Bs[kk][cb] = *(const float4*)(B + (size_t)(k0 + kk) * TN + cb);
        }
        __syncthreads();

#pragma unroll
        for (int kk = 0; kk < 16; kk++) {
            float4 av = *(const float4*)&As[kk][tr * 4];
            float a[4] = {av.x, av.y, av.z, av.w};
            float b[CPT];
#pragma unroll
            for (int j = 0; j < CPT; j += 4) {
                float4 bv = *(const float4*)&Bs[kk][tc * CPT + j];
                b[j] = bv.x; b[j + 1] = bv.y; b[j + 2] = bv.z; b[j + 3] = bv.w;
            }
#pragma unroll
            for (int i = 0; i < 4; i++)
#pragma unroll
                for (int j = 0; j < CPT; j++)
                    acc[i][j] = fmaf(a[i], b[j], acc[i][j]);
        }
        __syncthreads();
    }

#pragma unroll
    for (int i = 0; i < 4; i++) {
        int row = rowBase + tr * 4 + i;
        if (row < nrows) {
            float* dst = C + (size_t)row * ldc + tc * CPT;
#pragma unroll
            for (int j = 0; j < CPT; j++) {
                if (ACC) dst[j] += acc[i][j];
                else     dst[j] = acc[i][j];
            }
        }
    }
}

// ---------------------------------------------------------------- aggregation
// AGG[n][:] = H[n][:] * dinv[n]^2  (self-loop contribution == init, no memset)
__global__ void agg_init_kernel(const float* __restrict__ H, const float* __restrict__ dinv,
                                float* __restrict__ AGG, int n, int ch4 /* ch/4 */) {
    int i = blockIdx.x * blockDim.x + threadIdx.x;
    if (i >= n * ch4) return;
    int node = i / ch4;
    float d = dinv[node]; d = d * d;
    float4 v = ((const float4*)H)[i];
    v.x *= d; v.y *= d; v.z *= d; v.w *= d;
    ((float4*)AGG)[i] = v;
}

// one wave per edge, 128 channels (float2 per lane)
__global__ __launch_bounds__(256) void spmm128_kernel(
    const float* __restrict__ H, const int* __restrict__ row, const int* __restrict__ col,
    const float* __restrict__ norm, float* __restrict__ AGG, int E)
{
    int w = (blockIdx.x * 256 + threadIdx.x) >> 6;
    if (w >= E) return;
    int lane = threadIdx.x & 63;
    int r = row[w], c = col[w];
    float nm = norm[w];
    float2 hv = *(const float2*)(H + (size_t)r * 128 + lane * 2);
    float* dst = AGG + (size_t)c * 128 + lane * 2;
    atomAddF(dst,     hv.x * nm);
    atomAddF(dst + 1, hv.y * nm);
}

// one wave per edge, 64 channels (1 float per lane)
__global__ __launch_bounds__(256) void spmm64_kernel(
    const float* __restrict__ H, const int* __restrict__ row, const int* __restrict__ col,
    const float* __restrict__ norm, float* __restrict__ AGG, int E)
{
    int w = (blockIdx.x * 256 + threadIdx.x) >> 6;
    if (w >= E) return;
    int lane = threadIdx.x & 63;
    int r = row[w], c = col[w];
    float nm = norm[w];
    float hv = H[(size_t)r * 64 + lane];
    atomAddF(AGG + (size_t)c * 64 + lane, hv * nm);
}

// ---------------------------------------------------------------- pointwise
__global__ void zr_kernel(const float* __restrict__ AGG, const float* __restrict__ hidden,
                          const float* __restrict__ bz, const float* __restrict__ br,
                          float* __restrict__ Z, float* __restrict__ RH, int total /* n*64 */) {
    int idx = blockIdx.x * blockDim.x + threadIdx.x;
    if (idx >= total) return;
    int node = idx >> 6, c = idx & 63;
    float az = AGG[((size_t)node << 7) + c]      + bz[c];
    float ar = AGG[((size_t)node << 7) + 64 + c] + br[c];
    float z = 1.f / (1.f + __expf(-az));
    float r = 1.f / (1.f + __expf(-ar));
    Z[idx]  = z;
    RH[idx] = r * hidden[idx];
}

__global__ void final_kernel(const float* __restrict__ AGGH, const float* __restrict__ hidden,
                             const float* __restrict__ bh, const float* __restrict__ Z,
                             float* __restrict__ out, int total /* n*64 */) {
    int idx = blockIdx.x * blockDim.x + threadIdx.x;
    if (idx >= total) return;
    int c = idx & 63;
    float hc = tanhf(AGGH[idx] + bh[c]);
    float z  = Z[idx];
    out[idx] = z * hidden[idx] + (1.f - z) * hc;
}

// ---------------------------------------------------------------- launcher
extern "C" void kernel_launch(void* const* d_in, const int* in_sizes, int n_in,
                              void* d_out, int out_size, void* d_ws, size_t ws_size,
                              hipStream_t stream) {
    const float* x      = (const float*)d_in[0];
    const void*  eidx   = d_in[1];
    const float* ew     = (const float*)d_in[2];
    const float* hidden = (const float*)d_in[3];
    const float* Wz     = (const float*)d_in[4];
    const float* bz     = (const float*)d_in[5];
    const float* Wr     = (const float*)d_in[6];
    const float* br     = (const float*)d_in[7];
    const float* Wh     = (const float*)d_in[8];
    const float* bh     = (const float*)d_in[9];
    float* out = (float*)d_out;

    const int E = in_sizes[2];            // 800000
    const int N = in_sizes[3] / OUT_CH;   // 50000

    // workspace carve-up (256B aligned)
    char* base = (char*)d_ws;
    size_t off = 0;
    auto carve = [&](size_t bytes) -> char* {
        char* p = base + off;
        off = (off + bytes + 255) & ~(size_t)255;
        return p;
    };
    int*   row32 = (int*)  carve((size_t)E * 4);
    int*   col32 = (int*)  carve((size_t)E * 4);
    float* norm  = (float*)carve((size_t)E * 4);
    float* dinv  = (float*)carve((size_t)N * 4);           // deg -> dinv in place
    float* Hzr   = (float*)carve((size_t)N * 128 * 4);     // later reused: Z | RH
    float* AGG   = (float*)carve((size_t)N * 128 * 4);     // later reused: AGGH
    float* Hh    = (float*)carve((size_t)N * 64 * 4);
    float* Bzr   = (float*)carve((size_t)CAT_CH * 128 * 4);
    int*   flag  = (int*)  carve(4);
    if (off > ws_size) return;  // workspace too small; validation will flag it

    float* Z  = Hzr;                    // after spmm128, Hzr is dead
    float* RH = Hzr + (size_t)N * 64;
    float* AGGH = AGG;                  // after zr_kernel, AGG(zr) is dead

    const int B256 = 256;
    const int gE   = (E + B256 - 1) / B256;
    const int gN   = (N + B256 - 1) / B256;
    const int gM   = (N + 63) / 64;           // GEMM row tiles
    const int gNO  = (N * 64 + B256 - 1) / B256;

    // 1. edge dtype detect + convert to int32
    hipLaunchKernelGGL(detect_kernel, dim3(1), dim3(64), 0, stream,
                       (const unsigned int*)eidx, flag);
    hipLaunchKernelGGL(convert_kernel, dim3(gE), dim3(B256), 0, stream,
                       eidx, row32, col32, flag, E);

    // 2. degree -> dinv -> per-edge norm
    hipLaunchKernelGGL(deg_init_kernel, dim3(gN), dim3(B256), 0, stream, dinv, N);
    hipLaunchKernelGGL(deg_add_kernel, dim3(gE), dim3(B256), 0, stream, col32, ew, dinv, E);
    hipLaunchKernelGGL(dinv_kernel, dim3(gN), dim3(B256), 0, stream, dinv, N);
    hipLaunchKernelGGL(norm_kernel, dim3(gE), dim3(B256), 0, stream,
                       row32, col32, ew, dinv, norm, E);

    // 3. GEMMs: H_zr = [x|hidden] @ [Wz|Wr], H_h = x @ Wh_top
    hipLaunchKernelGGL(pack_bzr_kernel, dim3((CAT_CH * 128 + 255) / 256), dim3(B256), 0, stream,
                       Wz, Wr, Bzr);
    hipLaunchKernelGGL((gemm_kernel<CAT_CH, 128, false>), dim3(gM), dim3(B256), 0, stream,
                       x, IN_CH, hidden, OUT_CH, Bzr, Hzr, 128, N);
    hipLaunchKernelGGL((gemm_kernel<IN_CH, 64, false>), dim3(gM), dim3(B256), 0, stream,
                       x, IN_CH, (const float*)nullptr, 0, Wh, Hh, 64, N);

    // 4. z/r aggregation: init with self-loop term, scatter-add edges
    hipLaunchKernelGGL(agg_init_kernel, dim3((N * 32 + 255) / 256), dim3(B256), 0, stream,
                       Hzr, dinv, AGG, N, 32);
    hipLaunchKernelGGL(spmm128_kernel, dim3((E + 3) / 4), dim3(B256), 0, stream,
                       Hzr, row32, col32, norm, AGG, E);

    // 5. z, r, r*hidden
    hipLaunchKernelGGL(zr_kernel, dim3(gNO), dim3(B256), 0, stream,
                       AGG, hidden, bz, br, Z, RH, N * 64);

    // 6. H_h += (r*hidden) @ Wh_bottom
    hipLaunchKernelGGL((gemm_kernel<OUT_CH, 64, true>), dim3(gM), dim3(B256), 0, stream,
                       RH, OUT_CH, (const float*)nullptr, 0, Wh + (size_t)IN_CH * 64, Hh, 64, N);

    // 7. h-candidate aggregation
    hipLaunchKernelGGL(agg_init_kernel, dim3((N * 16 + 255) / 256), dim3(B256), 0, stream,
                       Hh, dinv, AGGH, N, 16);
    hipLaunchKernelGGL(spmm64_kernel, dim3((E + 3) / 4), dim3(B256), 0, stream,
                       Hh, row32, col32, norm, AGGH, E);

    // 8. GRU blend
    hipLaunchKernelGGL(final_kernel, dim3(gNO), dim3(B256), 0, stream,
                       AGGH, hidden, bh, Z, out, N * 64);
}

// Round 2
// 350.362 us; speedup vs baseline: 2.8849x; 2.8849x over previous
//
#include <hip/hip_runtime.h>
#include <hip/hip_bf16.h>
#include <cstdint>
#include <cstddef>

// ---------------------------------------------------------------- constants
#define IN_CH   128
#define OUT_CH  64
#define CAT_CH  192   // IN_CH + OUT_CH

__device__ __forceinline__ void atomAddF(float* p, float v) {
    __hip_atomic_fetch_add(p, v, __ATOMIC_RELAXED, __HIP_MEMORY_SCOPE_AGENT);
}

__device__ __forceinline__ float sigmoidf_(float x) {
    return 1.f / (1.f + __expf(-x));
}

// ---------------------------------------------------------------- dtype detect
// edge_index may be int64 (declared) or int32 (JAX x64 off). For int64 data of
// non-negative values < 2^31, every odd 32-bit word is zero. For int32 node ids
// (random in [0,50000)) odd words are essentially never all zero.
__global__ void detect_kernel(const unsigned int* __restrict__ ei, int* __restrict__ flag) {
    unsigned int v = ei[(threadIdx.x << 1) + 1];
    unsigned long long b = __ballot(v != 0u);
    if (threadIdx.x == 0) *flag = (b != 0ull) ? 1 : 0;   // 1 => int32 layout
}

__device__ __forceinline__ int load_col(const void* ei, int i, int E, int f) {
    return f ? ((const int*)ei)[E + i] : (int)((const long long*)ei)[E + i];
}
__device__ __forceinline__ int load_row(const void* ei, int i, int E, int f) {
    return f ? ((const int*)ei)[i] : (int)((const long long*)ei)[i];
}

// ---------------------------------------------------------------- degree / hist
__global__ void deg_init_kernel(float* __restrict__ deg, int* __restrict__ counts, int n) {
    int i = blockIdx.x * blockDim.x + threadIdx.x;
    if (i < n) { deg[i] = 1.0f; counts[i] = 0; }   // self-loop weight 1
}

// merged: weighted degree (float) + in-degree count (int)
__global__ void hist_kernel(const void* __restrict__ ei, const float* __restrict__ w,
                            float* __restrict__ deg, int* __restrict__ counts,
                            const int* __restrict__ flag, int E) {
    int i = blockIdx.x * blockDim.x + threadIdx.x;
    if (i >= E) return;
    int c = load_col(ei, i, E, *flag);
    atomAddF(&deg[c], w[i]);
    atomicAdd(&counts[c], 1);
}

__global__ void dinv_kernel(float* __restrict__ deg, int n) {
    int i = blockIdx.x * blockDim.x + threadIdx.x;
    if (i >= n) return;
    float d = deg[i];
    deg[i] = (d > 0.f) ? rsqrtf(d) : 0.f;
}

// ---------------------------------------------------------------- scan (3-phase)
__global__ __launch_bounds__(256) void scan1_kernel(const int* __restrict__ counts,
                                                    int* __restrict__ starts,
                                                    int* __restrict__ bsum, int n) {
    __shared__ int s[256];
    int i = blockIdx.x * 256 + threadIdx.x;
    int v = (i < n) ? counts[i] : 0;
    s[threadIdx.x] = v;
    __syncthreads();
#pragma unroll
    for (int d = 1; d < 256; d <<= 1) {
        int t = (threadIdx.x >= d) ? s[threadIdx.x - d] : 0;
        __syncthreads();
        s[threadIdx.x] += t;
        __syncthreads();
    }
    if (i < n) starts[i] = s[threadIdx.x] - v;   // exclusive
    if (threadIdx.x == 255) bsum[blockIdx.x] = s[255];
}

__global__ __launch_bounds__(256) void scan2_kernel(int* __restrict__ bsum, int nb) {
    __shared__ int s[256];
    int t = threadIdx.x;
    int v = (t < nb) ? bsum[t] : 0;
    s[t] = v;
    __syncthreads();
#pragma unroll
    for (int d = 1; d < 256; d <<= 1) {
        int u = (t >= d) ? s[t - d] : 0;
        __syncthreads();
        s[t] += u;
        __syncthreads();
    }
    if (t < nb) bsum[t] = s[t] - v;   // exclusive block offsets, in place
}

__global__ void scan3_kernel(int* __restrict__ starts, int* __restrict__ cursor,
                             const int* __restrict__ boff, int n, int E) {
    int i = blockIdx.x * blockDim.x + threadIdx.x;
    if (i == 0) starts[n] = E;   // sentinel
    if (i >= n) return;
    int v = starts[i] + boff[blockIdx.x];
    starts[i] = v;
    cursor[i] = v;
}

// ---------------------------------------------------------------- CSR scatter
// srow[pos] = src node, snorm[pos] = dinv[r]*w*dinv[c], grouped by dst node c
__global__ void scatter_kernel(const void* __restrict__ ei, const float* __restrict__ w,
                               const float* __restrict__ dinv, int* __restrict__ cursor,
                               int* __restrict__ srow, float* __restrict__ snorm,
                               const int* __restrict__ flag, int E) {
    int i = blockIdx.x * blockDim.x + threadIdx.x;
    if (i >= E) return;
    int f = *flag;
    int r = load_row(ei, i, E, f);
    int c = load_col(ei, i, E, f);
    float nm = dinv[r] * w[i] * dinv[c];
    int pos = atomicAdd(&cursor[c], 1);
    srow[pos] = r;
    snorm[pos] = nm;
}

// ---------------------------------------------------------------- weight pack
// Bzr[k*128 + c] = c<64 ? W_z[k][c] : W_r[k][c-64]   (k in [0,192))
__global__ void pack_bzr_kernel(const float* __restrict__ Wz, const float* __restrict__ Wr,
                                float* __restrict__ Bzr) {
    int i = blockIdx.x * blockDim.x + threadIdx.x;
    if (i >= CAT_CH * 128) return;
    int k = i >> 7, c = i & 127;
    Bzr[i] = (c < 64) ? Wz[k * 64 + c] : Wr[k * 64 + (c - 64)];
}

// ---------------------------------------------------------------- GEMM
// C(nrows x ldc, first TN cols) = [A0|A1](nrows x K) @ B(K x TN), fp32 vector.
// 256 threads, 64-row tile. Thread (tr,tc) owns 4 rows x CPT cols.
template <int K, int TN, bool ACC>
__global__ __launch_bounds__(256) void gemm_kernel(
    const float* __restrict__ A0, int a0w,
    const float* __restrict__ A1, int a1w,
    const float* __restrict__ B,
    float* __restrict__ C, int ldc, int nrows)
{
    __shared__ float As[16][64];
    __shared__ float Bs[16][TN];
    constexpr int CPT = TN / 16;

    const int t  = threadIdx.x;
    const int tr = t & 15;
    const int tc = t >> 4;
    const int rowBase = blockIdx.x * 64;

    float acc[4][CPT];
#pragma unroll
    for (int i = 0; i < 4; i++)
#pragma unroll
        for (int j = 0; j < CPT; j++) acc[i][j] = 0.f;

    const int ar  = t >> 2;   // 0..63 row in tile (A load)
    const int ac4 = t & 3;    // 0..3  k sub-chunk (A load)
    int arow = rowBase + ar;
    if (arow >= nrows) arow = nrows - 1;

    for (int k0 = 0; k0 < K; k0 += 16) {
        {
            int k = k0 + ac4 * 4;
            const float* src = (k < a0w) ? (A0 + (size_t)arow * a0w + k)
                                         : (A1 + (size_t)arow * a1w + (k - a0w));
            float4 v = *(const float4*)src;
            As[ac4 * 4 + 0][ar] = v.x;
            As[ac4 * 4 + 1][ar] = v.y;
            As[ac4 * 4 + 2][ar] = v.z;
            As[ac4 * 4 + 3][ar] = v.w;
        }
        if (TN == 128) {
            int kk = t >> 4;
            int cb = (t & 15) * 8;
            const float* src = B + (size_t)(k0 + kk) * TN + cb;
            *(float4*)&Bs[kk][cb]     = *(const float4*)src;
            *(float4*)&Bs[kk][cb + 4] = *(const float4*)(src + 4);
        } else {  // TN == 64
            int kk = t >> 4;
            int cb = (t & 15) * 4;
            *(float4*)&Bs[kk][cb] = *(const float4*)(B + (size_t)(k0 + kk) * TN + cb);
        }
        __syncthreads();

#pragma unroll
        for (int kk = 0; kk < 16; kk++) {
            float4 av = *(const float4*)&As[kk][tr * 4];
            float a[4] = {av.x, av.y, av.z, av.w};
            float b[CPT];
#pragma unroll
            for (int j = 0; j < CPT; j += 4) {
                float4 bv = *(const float4*)&Bs[kk][tc * CPT + j];
                b[j] = bv.x; b[j + 1] = bv.y; b[j + 2] = bv.z; b[j + 3] = bv.w;
            }
#pragma unroll
            for (int i = 0; i < 4; i++)
#pragma unroll
                for (int j = 0; j < CPT; j++)
                    acc[i][j] = fmaf(a[i], b[j], acc[i][j]);
        }
        __syncthreads();
    }

#pragma unroll
    for (int i = 0; i < 4; i++) {
        int row = rowBase + tr * 4 + i;
        if (row < nrows) {
            float* dst = C + (size_t)row * ldc + tc * CPT;
#pragma unroll
            for (int j = 0; j < CPT; j++) {
                if (ACC) dst[j] += acc[i][j];
                else     dst[j] = acc[i][j];
            }
        }
    }
}

// ---------------------------------------------------------------- SpMM (CSR gather)
// One wave per node. 128 channels of Hzr, fused z/r epilogue:
//   lane<32  -> z channels c=2*lane   : Z  = sigmoid(agg + bz)
//   lane>=32 -> r channels c=2*lane-64: RH = sigmoid(agg + br) * hidden
__global__ __launch_bounds__(256) void spmm_zr_kernel(
    const float* __restrict__ H, const int* __restrict__ srow,
    const float* __restrict__ snorm, const int* __restrict__ starts,
    const float* __restrict__ dinv, const float* __restrict__ hidden,
    const float* __restrict__ bz, const float* __restrict__ br,
    float* __restrict__ Z, float* __restrict__ RH, int N)
{
    int node = (blockIdx.x * 256 + threadIdx.x) >> 6;
    if (node >= N) return;
    int lane = threadIdx.x & 63;
    int s = starts[node], e = starts[node + 1];
    float d = dinv[node];
    const int ch = lane * 2;

    float2 acc = *(const float2*)(H + (size_t)node * 128 + ch);
    acc.x *= d * d; acc.y *= d * d;                        // self-loop term

    int j = s;
    for (; j + 1 < e; j += 2) {
        int   r0 = srow[j],  r1 = srow[j + 1];
        float n0 = snorm[j], n1 = snorm[j + 1];
        float2 h0 = *(const float2*)(H + (size_t)r0 * 128 + ch);
        float2 h1 = *(const float2*)(H + (size_t)r1 * 128 + ch);
        acc.x = fmaf(h0.x, n0, acc.x); acc.y = fmaf(h0.y, n0, acc.y);
        acc.x = fmaf(h1.x, n1, acc.x); acc.y = fmaf(h1.y, n1, acc.y);
    }
    if (j < e) {
        int r0 = srow[j]; float n0 = snorm[j];
        float2 h0 = *(const float2*)(H + (size_t)r0 * 128 + ch);
        acc.x = fmaf(h0.x, n0, acc.x); acc.y = fmaf(h0.y, n0, acc.y);
    }

    if (lane < 32) {
        int c = ch;                                        // 0..62
        float* dst = Z + (size_t)node * 64 + c;
        dst[0] = sigmoidf_(acc.x + bz[c]);
        dst[1] = sigmoidf_(acc.y + bz[c + 1]);
    } else {
        int c = ch - 64;                                   // 0..62
        const float* hid = hidden + (size_t)node * 64 + c;
        float* dst = RH + (size_t)node * 64 + c;
        dst[0] = sigmoidf_(acc.x + br[c]) * hid[0];
        dst[1] = sigmoidf_(acc.y + br[c + 1]) * hid[1];
    }
}

// One wave per node, 64 channels of Hh, fused tanh + GRU blend -> out
__global__ __launch_bounds__(256) void spmm_h_kernel(
    const float* __restrict__ H, const int* __restrict__ srow,
    const float* __restrict__ snorm, const int* __restrict__ starts,
    const float* __restrict__ dinv, const float* __restrict__ hidden,
    const float* __restrict__ bh, const float* __restrict__ Z,
    float* __restrict__ out, int N)
{
    int node = (blockIdx.x * 256 + threadIdx.x) >> 6;
    if (node >= N) return;
    int lane = threadIdx.x & 63;
    int s = starts[node], e = starts[node + 1];
    float d = dinv[node];

    float acc = H[(size_t)node * 64 + lane] * d * d;       // self-loop term

    int j = s;
    for (; j + 1 < e; j += 2) {
        int   r0 = srow[j],  r1 = srow[j + 1];
        float n0 = snorm[j], n1 = snorm[j + 1];
        float h0 = H[(size_t)r0 * 64 + lane];
        float h1 = H[(size_t)r1 * 64 + lane];
        acc = fmaf(h0, n0, acc);
        acc = fmaf(h1, n1, acc);
    }
    if (j < e) acc = fmaf(H[(size_t)srow[j] * 64 + lane], snorm[j], acc);

    size_t idx = (size_t)node * 64 + lane;
    float hc = tanhf(acc + bh[lane]);
    float z  = Z[idx];
    out[idx] = z * hidden[idx] + (1.f - z) * hc;
}

// ---------------------------------------------------------------- launcher
extern "C" void kernel_launch(void* const* d_in, const int* in_sizes, int n_in,
                              void* d_out, int out_size, void* d_ws, size_t ws_size,
                              hipStream_t stream) {
    const float* x      = (const float*)d_in[0];
    const void*  eidx   = d_in[1];
    const float* ew     = (const float*)d_in[2];
    const float* hidden = (const float*)d_in[3];
    const float* Wz     = (const float*)d_in[4];
    const float* bz     = (const float*)d_in[5];
    const float* Wr     = (const float*)d_in[6];
    const float* br     = (const float*)d_in[7];
    const float* Wh     = (const float*)d_in[8];
    const float* bh     = (const float*)d_in[9];
    float* out = (float*)d_out;

    const int E = in_sizes[2];            // 800000
    const int N = in_sizes[3] / OUT_CH;   // 50000

    // workspace carve-up (256B aligned)
    char* base = (char*)d_ws;
    size_t off = 0;
    auto carve = [&](size_t bytes) -> char* {
        char* p = base + off;
        off = (off + bytes + 255) & ~(size_t)255;
        return p;
    };
    float* dinv   = (float*)carve((size_t)N * 4);            // deg -> dinv in place
    int*   counts = (int*)  carve((size_t)N * 4);            // -> cursor after scan
    int*   starts = (int*)  carve((size_t)(N + 1) * 4);
    int*   bsum   = (int*)  carve(256 * 4);
    int*   srow   = (int*)  carve((size_t)E * 4);
    float* snorm  = (float*)carve((size_t)E * 4);
    float* Hzr    = (float*)carve((size_t)N * 128 * 4);
    float* Hh     = (float*)carve((size_t)N * 64 * 4);
    float* Z      = (float*)carve((size_t)N * 64 * 4);
    float* RH     = (float*)carve((size_t)N * 64 * 4);
    float* Bzr    = (float*)carve((size_t)CAT_CH * 128 * 4);
    int*   flag   = (int*)  carve(4);
    if (off > ws_size) return;  // workspace too small; validation will flag it
    int* cursor = counts;       // counts is dead after scan1

    const int B256 = 256;
    const int gE  = (E + B256 - 1) / B256;
    const int gN  = (N + B256 - 1) / B256;    // also = #scan blocks (<=256 req)
    const int gM  = (N + 63) / 64;            // GEMM row tiles
    const int gW  = (N + 3) / 4;              // one wave per node

    // 1. edge dtype detect
    hipLaunchKernelGGL(detect_kernel, dim3(1), dim3(64), 0, stream,
                       (const unsigned int*)eidx, flag);

    // 2. histogram: weighted degree + in-degree counts
    hipLaunchKernelGGL(deg_init_kernel, dim3(gN), dim3(B256), 0, stream, dinv, counts, N);
    hipLaunchKernelGGL(hist_kernel, dim3(gE), dim3(B256), 0, stream,
                       eidx, ew, dinv, counts, flag, E);
    hipLaunchKernelGGL(dinv_kernel, dim3(gN), dim3(B256), 0, stream, dinv, N);

    // 3. exclusive scan of counts -> starts (+ cursor copy)
    hipLaunchKernelGGL(scan1_kernel, dim3(gN), dim3(B256), 0, stream, counts, starts, bsum, N);
    hipLaunchKernelGGL(scan2_kernel, dim3(1), dim3(B256), 0, stream, bsum, gN);
    hipLaunchKernelGGL(scan3_kernel, dim3(gN), dim3(B256), 0, stream, starts, cursor, bsum, N, E);

    // 4. CSR scatter: (srow, snorm) grouped by destination
    hipLaunchKernelGGL(scatter_kernel, dim3(gE), dim3(B256), 0, stream,
                       eidx, ew, dinv, cursor, srow, snorm, flag, E);

    // 5. GEMMs: Hzr = [x|hidden] @ [Wz|Wr], Hh = x @ Wh_top
    hipLaunchKernelGGL(pack_bzr_kernel, dim3((CAT_CH * 128 + 255) / 256), dim3(B256), 0, stream,
                       Wz, Wr, Bzr);
    hipLaunchKernelGGL((gemm_kernel<CAT_CH, 128, false>), dim3(gM), dim3(B256), 0, stream,
                       x, IN_CH, hidden, OUT_CH, Bzr, Hzr, 128, N);
    hipLaunchKernelGGL((gemm_kernel<IN_CH, 64, false>), dim3(gM), dim3(B256), 0, stream,
                       x, IN_CH, (const float*)nullptr, 0, Wh, Hh, 64, N);

    // 6. z/r aggregation (CSR gather) + fused sigmoid epilogue -> Z, RH
    hipLaunchKernelGGL(spmm_zr_kernel, dim3(gW), dim3(B256), 0, stream,
                       Hzr, srow, snorm, starts, dinv, hidden, bz, br, Z, RH, N);

    // 7. Hh += (r*hidden) @ Wh_bottom
    hipLaunchKernelGGL((gemm_kernel<OUT_CH, 64, true>), dim3(gM), dim3(B256), 0, stream,
                       RH, OUT_CH, (const float*)nullptr, 0, Wh + (size_t)IN_CH * 64, Hh, 64, N);

    // 8. h-candidate aggregation + fused tanh/GRU blend -> out
    hipLaunchKernelGGL(spmm_h_kernel, dim3(gW), dim3(B256), 0, stream,
                       Hh, srow, snorm, starts, dinv, hidden, bh, Z, out, N);
}

// Round 3
// 220.785 us; speedup vs baseline: 4.5780x; 1.5869x over previous
//
#include <hip/hip_runtime.h>
#include <hip/hip_bf16.h>
#include <cstdint>
#include <cstddef>

// ---------------------------------------------------------------- constants
#define IN_CH   128
#define OUT_CH  64
#define CAT_CH  192   // IN_CH + OUT_CH

typedef short bf16x8 __attribute__((ext_vector_type(8)));
typedef float f32x4  __attribute__((ext_vector_type(4)));
typedef unsigned long long u64;
typedef unsigned int u32;

__device__ __forceinline__ float sigmoidf_(float x) { return 1.f / (1.f + __expf(-x)); }

// fp32 -> bf16 (RNE)
__device__ __forceinline__ unsigned short f2bf(float f) {
    u32 u = __float_as_uint(f);
    u32 r = (u + 0x7fffu + ((u >> 16) & 1u)) >> 16;
    return (unsigned short)r;
}
__device__ __forceinline__ float bflo(u32 v) { return __uint_as_float(v << 16); }
__device__ __forceinline__ float bfhi(u32 v) { return __uint_as_float(v & 0xffff0000u); }
__device__ __forceinline__ float bf1(unsigned short v) { return __uint_as_float((u32)v << 16); }

// ---------------------------------------------------------------- dtype detect
// edge_index may be int64 (declared) or int32 (JAX x64 off). For int64 data of
// values < 2^31, every odd 32-bit word is zero.
__global__ void detect_kernel(const unsigned int* __restrict__ ei, int* __restrict__ flag) {
    unsigned int v = ei[(threadIdx.x << 1) + 1];
    unsigned long long b = __ballot(v != 0u);
    if (threadIdx.x == 0) *flag = (b != 0ull) ? 1 : 0;   // 1 => int32 layout
}

__device__ __forceinline__ int load_col(const void* ei, int i, int E, int f) {
    return f ? ((const int*)ei)[E + i] : (int)((const long long*)ei)[E + i];
}
__device__ __forceinline__ int load_row(const void* ei, int i, int E, int f) {
    return f ? ((const int*)ei)[i] : (int)((const long long*)ei)[i];
}

// ---------------------------------------------------------------- preprocessing
__global__ void zero_kernel(u64* __restrict__ packed, int n) {
    int i = blockIdx.x * blockDim.x + threadIdx.x;
    if (i < n) packed[i] = 0ull;
}

// one u64 atomic per edge: high32 = count, low32 = sum(w) in 2^-20 fixed point.
// Returned old count == this edge's rank within its destination bucket.
__global__ void hist2_kernel(const void* __restrict__ ei, const float* __restrict__ w,
                             u64* __restrict__ packed, u32* __restrict__ rank,
                             const int* __restrict__ flag, int E) {
    int i = blockIdx.x * blockDim.x + threadIdx.x;
    if (i >= E) return;
    int c = load_col(ei, i, E, *flag);
    u32 wq = __float2uint_rn(w[i] * 1048576.0f);     // 2^20 scale
    u64 old = atomicAdd(&packed[c], (1ull << 32) | (u64)wq);
    rank[i] = (u32)(old >> 32);
}

// unpack: dinv = rsqrt(1 + wsum), counts for scan
__global__ void dinvc_kernel(const u64* __restrict__ packed, float* __restrict__ dinv,
                             int* __restrict__ counts, int n) {
    int i = blockIdx.x * blockDim.x + threadIdx.x;
    if (i >= n) return;
    u64 p = packed[i];
    float wsum = (float)(u32)(p & 0xffffffffull) * (1.0f / 1048576.0f);
    dinv[i] = rsqrtf(1.0f + wsum);                   // self-loop weight 1 => deg >= 1
    counts[i] = (int)(p >> 32);
}

// ---------------------------------------------------------------- scan (3-phase)
__global__ __launch_bounds__(256) void scan1_kernel(const int* __restrict__ counts,
                                                    int* __restrict__ starts,
                                                    int* __restrict__ bsum, int n) {
    __shared__ int s[256];
    int i = blockIdx.x * 256 + threadIdx.x;
    int v = (i < n) ? counts[i] : 0;
    s[threadIdx.x] = v;
    __syncthreads();
#pragma unroll
    for (int d = 1; d < 256; d <<= 1) {
        int t = (threadIdx.x >= d) ? s[threadIdx.x - d] : 0;
        __syncthreads();
        s[threadIdx.x] += t;
        __syncthreads();
    }
    if (i < n) starts[i] = s[threadIdx.x] - v;   // exclusive
    if (threadIdx.x == 255) bsum[blockIdx.x] = s[255];
}

__global__ __launch_bounds__(256) void scan2_kernel(int* __restrict__ bsum, int nb) {
    __shared__ int s[256];
    int t = threadIdx.x;
    int v = (t < nb) ? bsum[t] : 0;
    s[t] = v;
    __syncthreads();
#pragma unroll
    for (int d = 1; d < 256; d <<= 1) {
        int u = (t >= d) ? s[t - d] : 0;
        __syncthreads();
        s[t] += u;
        __syncthreads();
    }
    if (t < nb) bsum[t] = s[t] - v;   // exclusive block offsets, in place
}

__global__ void scan3_kernel(int* __restrict__ starts, const int* __restrict__ boff,
                             int n, int E) {
    int i = blockIdx.x * blockDim.x + threadIdx.x;
    if (i == 0) starts[n] = E;   // sentinel
    if (i < n) starts[i] += boff[blockIdx.x];
}

// ---------------------------------------------------------------- CSR scatter (atomic-free)
// pairs[pos] = {src (low32), norm (high32)} grouped by destination
__global__ void scatter2_kernel(const void* __restrict__ ei, const float* __restrict__ w,
                                const float* __restrict__ dinv, const int* __restrict__ starts,
                                const u32* __restrict__ rank, u64* __restrict__ pairs,
                                const int* __restrict__ flag, int E) {
    int i = blockIdx.x * blockDim.x + threadIdx.x;
    if (i >= E) return;
    int f = *flag;
    int r = load_row(ei, i, E, f);
    int c = load_col(ei, i, E, f);
    float nm = dinv[r] * w[i] * dinv[c];
    int pos = starts[c] + (int)rank[i];
    pairs[pos] = ((u64)__float_as_uint(nm) << 32) | (u32)r;
}

// ---------------------------------------------------------------- fp32 -> bf16 convert
// xb = bf16(x) [N*128], hb = bf16(hidden) [N*64]
__global__ void cvt_kernel(const float* __restrict__ x, const float* __restrict__ hidden,
                           unsigned short* __restrict__ xb, unsigned short* __restrict__ hb,
                           int nx, int nh) {
    int i4 = (blockIdx.x * blockDim.x + threadIdx.x) * 4;
    if (i4 < nx) {
        float4 v = *(const float4*)&x[i4];
        ushort4 o = { f2bf(v.x), f2bf(v.y), f2bf(v.z), f2bf(v.w) };
        *(ushort4*)&xb[i4] = o;
    } else {
        int j = i4 - nx;
        if (j < nh) {
            float4 v = *(const float4*)&hidden[j];
            ushort4 o = { f2bf(v.x), f2bf(v.y), f2bf(v.z), f2bf(v.w) };
            *(ushort4*)&hb[j] = o;
        }
    }
}

// ---------------------------------------------------------------- weight pack (k-major bf16)
// Bzrt[col][k], col<64 from Wz[:,col], col in 64..127 from Wr[:,col-64]
// Wht[col][k]  = Wh[k][col]
__global__ void packW_kernel(const float* __restrict__ Wz, const float* __restrict__ Wr,
                             const float* __restrict__ Wh,
                             unsigned short* __restrict__ Bzrt, unsigned short* __restrict__ Wht) {
    int i = blockIdx.x * blockDim.x + threadIdx.x;
    if (i >= 192 * CAT_CH) return;
    int col = i / CAT_CH, k = i % CAT_CH;
    if (col < 128) {
        float v = (col < 64) ? Wz[k * 64 + col] : Wr[k * 64 + (col - 64)];
        Bzrt[col * CAT_CH + k] = f2bf(v);
    } else {
        Wht[(col - 128) * CAT_CH + k] = f2bf(Wh[k * 64 + (col - 128)]);
    }
}

// ---------------------------------------------------------------- bf16 MFMA GEMM
// C[M][TN] bf16 = [A0 | A1]([M][a0w] ++ [M][a1w], K=192 bf16) @ Bt([TN][192] bf16)
// 256 threads = 4 waves; block tile 128 rows; wave owns 32 rows x TN cols.
// mfma_f32_16x16x32_bf16: A frag a[j] = A[lane&15][(lane>>4)*8+j],
// B frag b[j] = B[(lane>>4)*8+j][lane&15], C: col=lane&15, row=(lane>>4)*4+reg.
template <int TN>
__global__ __launch_bounds__(256) void gemm_bf16_kernel(
    const unsigned short* __restrict__ A0, int a0w,
    const unsigned short* __restrict__ A1, int a1w,
    const unsigned short* __restrict__ Bt,
    unsigned short* __restrict__ C, int nrows)
{
    __shared__ unsigned short As[128][48];    // 32 k + 16 pad (96B rows, 16B aligned)
    __shared__ unsigned short Bs[TN][200];    // 192 k + 8 pad (400B rows, 16B aligned)

    const int t = threadIdx.x, lane = t & 63, wave = t >> 6;
    const int rowBase = blockIdx.x * 128;

    // stage all of Bt once (16B chunks; 192 % 8 == 0 keeps chunks within a row)
    for (int idx = t * 8; idx < TN * CAT_CH; idx += 256 * 8) {
        int col = idx / CAT_CH, k = idx % CAT_CH;
        *(int4*)&Bs[col][k] = *(const int4*)&Bt[idx];
    }

    f32x4 acc[2][TN / 16];
#pragma unroll
    for (int rf = 0; rf < 2; rf++)
#pragma unroll
        for (int cf = 0; cf < TN / 16; cf++) acc[rf][cf] = (f32x4){0.f, 0.f, 0.f, 0.f};

    const int srow = t >> 1, half = t & 1;     // A staging: 2 threads/row, 32B each
    int arow = rowBase + srow;
    if (arow >= nrows) arow = nrows - 1;

    for (int k0 = 0; k0 < CAT_CH; k0 += 32) {
        __syncthreads();   // prev compute done (also orders first B stage)
        {
            const unsigned short* src = (k0 < a0w)
                ? A0 + (size_t)arow * a0w + k0
                : A1 + (size_t)arow * a1w + (k0 - a0w);
            *(int4*)&As[srow][half * 16] = *(const int4*)(src + half * 16);
            *(int4*)&As[srow][half * 16 + 8] = *(const int4*)(src + half * 16 + 8);
        }
        __syncthreads();

        const int rbase = wave * 32;
        const int koff = (lane >> 4) * 8;
        bf16x8 a0 = *(const bf16x8*)&As[rbase + (lane & 15)][koff];
        bf16x8 a1 = *(const bf16x8*)&As[rbase + 16 + (lane & 15)][koff];
#pragma unroll
        for (int cf = 0; cf < TN / 16; cf++) {
            bf16x8 b = *(const bf16x8*)&Bs[cf * 16 + (lane & 15)][k0 + koff];
            acc[0][cf] = __builtin_amdgcn_mfma_f32_16x16x32_bf16(a0, b, acc[0][cf], 0, 0, 0);
            acc[1][cf] = __builtin_amdgcn_mfma_f32_16x16x32_bf16(a1, b, acc[1][cf], 0, 0, 0);
        }
    }

#pragma unroll
    for (int rf = 0; rf < 2; rf++)
#pragma unroll
        for (int cf = 0; cf < TN / 16; cf++) {
            int row0 = rowBase + wave * 32 + rf * 16 + (lane >> 4) * 4;
            int col  = cf * 16 + (lane & 15);
#pragma unroll
            for (int r = 0; r < 4; r++) {
                int row = row0 + r;
                if (row < nrows) C[(size_t)row * TN + col] = f2bf(acc[rf][cf][r]);
            }
        }
}

// ---------------------------------------------------------------- SpMM (CSR gather, bf16 H)
// One wave per node, 128 ch of Hzrb (2 ch/lane), fused z/r epilogue.
__global__ __launch_bounds__(256) void spmm_zr_kernel(
    const unsigned short* __restrict__ H, const u64* __restrict__ pairs,
    const int* __restrict__ starts, const float* __restrict__ dinv,
    const float* __restrict__ hidden, const float* __restrict__ bz,
    const float* __restrict__ br, float* __restrict__ Z,
    unsigned short* __restrict__ RHb, int N)
{
    int node = (blockIdx.x * 256 + threadIdx.x) >> 6;
    if (node >= N) return;
    int lane = threadIdx.x & 63;
    int s = starts[node], e = starts[node + 1];
    float d = dinv[node], d2 = d * d;
    const int ch = lane * 2;

    u32 self = *(const u32*)&H[(size_t)node * 128 + ch];
    float ax = bflo(self) * d2, ay = bfhi(self) * d2;

    int j = s;
    for (; j + 1 < e; j += 2) {
        u64 p0 = pairs[j], p1 = pairs[j + 1];
        int r0 = (int)(u32)p0, r1 = (int)(u32)p1;
        float n0 = __uint_as_float((u32)(p0 >> 32));
        float n1 = __uint_as_float((u32)(p1 >> 32));
        u32 h0 = *(const u32*)&H[(size_t)r0 * 128 + ch];
        u32 h1 = *(const u32*)&H[(size_t)r1 * 128 + ch];
        ax = fmaf(bflo(h0), n0, ax); ay = fmaf(bfhi(h0), n0, ay);
        ax = fmaf(bflo(h1), n1, ax); ay = fmaf(bfhi(h1), n1, ay);
    }
    if (j < e) {
        u64 p0 = pairs[j];
        int r0 = (int)(u32)p0;
        float n0 = __uint_as_float((u32)(p0 >> 32));
        u32 h0 = *(const u32*)&H[(size_t)r0 * 128 + ch];
        ax = fmaf(bflo(h0), n0, ax); ay = fmaf(bfhi(h0), n0, ay);
    }

    if (lane < 32) {
        int c = ch;                                 // z channels 0..62
        float2 o = { sigmoidf_(ax + bz[c]), sigmoidf_(ay + bz[c + 1]) };
        *(float2*)&Z[(size_t)node * 64 + c] = o;
    } else {
        int c = ch - 64;                            // r channels 0..62
        const float* hid = hidden + (size_t)node * 64 + c;
        float rh0 = sigmoidf_(ax + br[c])     * hid[0];
        float rh1 = sigmoidf_(ay + br[c + 1]) * hid[1];
        u32 packed = (u32)f2bf(rh0) | ((u32)f2bf(rh1) << 16);
        *(u32*)&RHb[(size_t)node * 64 + c] = packed;
    }
}

// One wave per node, 64 ch of Hhb, fused tanh + GRU blend -> out
__global__ __launch_bounds__(256) void spmm_h_kernel(
    const unsigned short* __restrict__ H, const u64* __restrict__ pairs,
    const int* __restrict__ starts, const float* __restrict__ dinv,
    const float* __restrict__ hidden, const float* __restrict__ bh,
    const float* __restrict__ Z, float* __restrict__ out, int N)
{
    int node = (blockIdx.x * 256 + threadIdx.x) >> 6;
    if (node >= N) return;
    int lane = threadIdx.x & 63;
    int s = starts[node], e = starts[node + 1];
    float d = dinv[node], d2 = d * d;

    float acc = bf1(H[(size_t)node * 64 + lane]) * d2;

    int j = s;
    for (; j + 1 < e; j += 2) {
        u64 p0 = pairs[j], p1 = pairs[j + 1];
        int r0 = (int)(u32)p0, r1 = (int)(u32)p1;
        float n0 = __uint_as_float((u32)(p0 >> 32));
        float n1 = __uint_as_float((u32)(p1 >> 32));
        acc = fmaf(bf1(H[(size_t)r0 * 64 + lane]), n0, acc);
        acc = fmaf(bf1(H[(size_t)r1 * 64 + lane]), n1, acc);
    }
    if (j < e) {
        u64 p0 = pairs[j];
        acc = fmaf(bf1(H[(size_t)((u32)p0) * 64 + lane]),
                   __uint_as_float((u32)(p0 >> 32)), acc);
    }

    size_t idx = (size_t)node * 64 + lane;
    float hc = tanhf(acc + bh[lane]);
    float z  = Z[idx];
    out[idx] = z * hidden[idx] + (1.f - z) * hc;
}

// ---------------------------------------------------------------- launcher
extern "C" void kernel_launch(void* const* d_in, const int* in_sizes, int n_in,
                              void* d_out, int out_size, void* d_ws, size_t ws_size,
                              hipStream_t stream) {
    const float* x      = (const float*)d_in[0];
    const void*  eidx   = d_in[1];
    const float* ew     = (const float*)d_in[2];
    const float* hidden = (const float*)d_in[3];
    const float* Wz     = (const float*)d_in[4];
    const float* bz     = (const float*)d_in[5];
    const float* Wr     = (const float*)d_in[6];
    const float* br     = (const float*)d_in[7];
    const float* Wh     = (const float*)d_in[8];
    const float* bh     = (const float*)d_in[9];
    float* out = (float*)d_out;

    const int E = in_sizes[2];            // 800000
    const int N = in_sizes[3] / OUT_CH;   // 50000

    // workspace carve-up (256B aligned)
    char* base = (char*)d_ws;
    size_t off = 0;
    auto carve = [&](size_t bytes) -> char* {
        char* p = base + off;
        off = (off + bytes + 255) & ~(size_t)255;
        return p;
    };
    u64*   packed = (u64*)  carve((size_t)N * 8);
    u32*   rank   = (u32*)  carve((size_t)E * 4);
    float* dinv   = (float*)carve((size_t)N * 4);
    int*   counts = (int*)  carve((size_t)N * 4);
    int*   starts = (int*)  carve((size_t)(N + 1) * 4);
    int*   bsum   = (int*)  carve(256 * 4);
    u64*   pairs  = (u64*)  carve((size_t)E * 8);
    unsigned short* xb   = (unsigned short*)carve((size_t)N * 128 * 2);
    unsigned short* hb   = (unsigned short*)carve((size_t)N * 64 * 2);
    unsigned short* Hzrb = (unsigned short*)carve((size_t)N * 128 * 2);
    unsigned short* RHb  = (unsigned short*)carve((size_t)N * 64 * 2);
    unsigned short* Hhb  = (unsigned short*)carve((size_t)N * 64 * 2);
    float* Z = (float*)carve((size_t)N * 64 * 4);
    unsigned short* Bzrt = (unsigned short*)carve((size_t)128 * CAT_CH * 2);
    unsigned short* Wht  = (unsigned short*)carve((size_t)64 * CAT_CH * 2);
    int* flag = (int*)carve(4);
    if (off > ws_size) return;

    const int B256 = 256;
    const int gE = (E + B256 - 1) / B256;
    const int gN = (N + B256 - 1) / B256;     // scan blocking (<=256 blocks)
    const int gM = (N + 127) / 128;           // GEMM row tiles
    const int gW = (N + 3) / 4;               // one wave per node

    // 1. dtype detect
    hipLaunchKernelGGL(detect_kernel, dim3(1), dim3(64), 0, stream,
                       (const unsigned int*)eidx, flag);

    // 2. packed histogram (count | sum w) + per-edge rank
    hipLaunchKernelGGL(zero_kernel, dim3(gN), dim3(B256), 0, stream, packed, N);
    hipLaunchKernelGGL(hist2_kernel, dim3(gE), dim3(B256), 0, stream,
                       eidx, ew, packed, rank, flag, E);
    hipLaunchKernelGGL(dinvc_kernel, dim3(gN), dim3(B256), 0, stream,
                       packed, dinv, counts, N);

    // 3. exclusive scan -> starts
    hipLaunchKernelGGL(scan1_kernel, dim3(gN), dim3(B256), 0, stream, counts, starts, bsum, N);
    hipLaunchKernelGGL(scan2_kernel, dim3(1), dim3(B256), 0, stream, bsum, gN);
    hipLaunchKernelGGL(scan3_kernel, dim3(gN), dim3(B256), 0, stream, starts, bsum, N, E);

    // 4. atomic-free CSR scatter
    hipLaunchKernelGGL(scatter2_kernel, dim3(gE), dim3(B256), 0, stream,
                       eidx, ew, dinv, starts, rank, pairs, flag, E);

    // 5. bf16 conversions + weight packs
    hipLaunchKernelGGL(cvt_kernel, dim3((N * CAT_CH / 4 + 255) / 256), dim3(B256), 0, stream,
                       x, hidden, xb, hb, N * 128, N * 64);
    hipLaunchKernelGGL(packW_kernel, dim3((192 * CAT_CH + 255) / 256), dim3(B256), 0, stream,
                       Wz, Wr, Wh, Bzrt, Wht);

    // 6. GEMM1: Hzrb = [xb|hb] @ [Wz|Wr]   (bf16 MFMA)
    hipLaunchKernelGGL((gemm_bf16_kernel<128>), dim3(gM), dim3(B256), 0, stream,
                       xb, 128, hb, 64, Bzrt, Hzrb, N);

    // 7. z/r aggregation + sigmoid epilogue -> Z (fp32), RHb (bf16)
    hipLaunchKernelGGL(spmm_zr_kernel, dim3(gW), dim3(B256), 0, stream,
                       Hzrb, pairs, starts, dinv, hidden, bz, br, Z, RHb, N);

    // 8. GEMM2: Hhb = [xb|RHb] @ Wh   (single fused K=192 GEMM)
    hipLaunchKernelGGL((gemm_bf16_kernel<64>), dim3(gM), dim3(B256), 0, stream,
                       xb, 128, RHb, 64, Wht, Hhb, N);

    // 9. h-candidate aggregation + tanh/GRU blend -> out
    hipLaunchKernelGGL(spmm_h_kernel, dim3(gW), dim3(B256), 0, stream,
                       Hhb, pairs, starts, dinv, hidden, bh, Z, out, N);
}

// Round 4
// 202.823 us; speedup vs baseline: 4.9834x; 1.0886x over previous
//
#include <hip/hip_runtime.h>
#include <hip/hip_bf16.h>
#include <cstdint>
#include <cstddef>

// ---------------------------------------------------------------- constants
#define IN_CH   128
#define OUT_CH  64
#define CAT_CH  192   // IN_CH + OUT_CH

typedef short bf16x8 __attribute__((ext_vector_type(8)));
typedef float f32x4  __attribute__((ext_vector_type(4)));
typedef unsigned long long u64;
typedef unsigned int u32;

__device__ __forceinline__ float sigmoidf_(float x) { return 1.f / (1.f + __expf(-x)); }

// fp32 -> bf16 (RNE)
__device__ __forceinline__ unsigned short f2bf(float f) {
    u32 u = __float_as_uint(f);
    u32 r = (u + 0x7fffu + ((u >> 16) & 1u)) >> 16;
    return (unsigned short)r;
}
__device__ __forceinline__ float bflo(u32 v) { return __uint_as_float(v << 16); }
__device__ __forceinline__ float bfhi(u32 v) { return __uint_as_float(v & 0xffff0000u); }
__device__ __forceinline__ float bf1(unsigned short v) { return __uint_as_float((u32)v << 16); }

// ---------------------------------------------------------------- dtype detect
// edge_index may be int64 (declared) or int32 (JAX x64 off). For int64 data of
// values < 2^31, every odd 32-bit word is zero.
__global__ void detect_kernel(const unsigned int* __restrict__ ei, int* __restrict__ flag) {
    unsigned int v = ei[(threadIdx.x << 1) + 1];
    unsigned long long b = __ballot(v != 0u);
    if (threadIdx.x == 0) *flag = (b != 0ull) ? 1 : 0;   // 1 => int32 layout
}

__device__ __forceinline__ int load_col(const void* ei, int i, int E, int f) {
    return f ? ((const int*)ei)[E + i] : (int)((const long long*)ei)[E + i];
}
__device__ __forceinline__ int load_row(const void* ei, int i, int E, int f) {
    return f ? ((const int*)ei)[i] : (int)((const long long*)ei)[i];
}

// ---------------------------------------------------------------- preprocessing
// one u64 atomic per edge: high32 = count, low32 = sum(w) in 2^-20 fixed point.
// Returned old count == this edge's rank within its destination bucket.
// 4 edges/thread for atomic-latency ILP.
__global__ void hist2_kernel(const void* __restrict__ ei, const float* __restrict__ w,
                             u64* __restrict__ packed, u32* __restrict__ rank,
                             const int* __restrict__ flag, int E) {
    int i0 = (blockIdx.x * blockDim.x + threadIdx.x) * 4;
    if (i0 >= E) return;
    int f = *flag;
    u32 rk[4];
#pragma unroll
    for (int k = 0; k < 4; k++) {
        int i = i0 + k;
        if (i < E) {
            int c = load_col(ei, i, E, f);
            u32 wq = __float2uint_rn(w[i] * 1048576.0f);     // 2^20 scale
            u64 old = atomicAdd(&packed[c], (1ull << 32) | (u64)wq);
            rk[k] = (u32)(old >> 32);
        }
    }
#pragma unroll
    for (int k = 0; k < 4; k++)
        if (i0 + k < E) rank[i0 + k] = rk[k];
}

// unpack: dinv = rsqrt(1 + wsum), counts for scan
__global__ void dinvc_kernel(const u64* __restrict__ packed, float* __restrict__ dinv,
                             int* __restrict__ counts, int n) {
    int i = blockIdx.x * blockDim.x + threadIdx.x;
    if (i >= n) return;
    u64 p = packed[i];
    float wsum = (float)(u32)(p & 0xffffffffull) * (1.0f / 1048576.0f);
    dinv[i] = rsqrtf(1.0f + wsum);                   // self-loop weight 1 => deg >= 1
    counts[i] = (int)(p >> 32);
}

// ---------------------------------------------------------------- scan (3-phase)
__global__ __launch_bounds__(256) void scan1_kernel(const int* __restrict__ counts,
                                                    int* __restrict__ starts,
                                                    int* __restrict__ bsum, int n) {
    __shared__ int s[256];
    int i = blockIdx.x * 256 + threadIdx.x;
    int v = (i < n) ? counts[i] : 0;
    s[threadIdx.x] = v;
    __syncthreads();
#pragma unroll
    for (int d = 1; d < 256; d <<= 1) {
        int t = (threadIdx.x >= d) ? s[threadIdx.x - d] : 0;
        __syncthreads();
        s[threadIdx.x] += t;
        __syncthreads();
    }
    if (i < n) starts[i] = s[threadIdx.x] - v;   // exclusive
    if (threadIdx.x == 255) bsum[blockIdx.x] = s[255];
}

__global__ __launch_bounds__(256) void scan2_kernel(int* __restrict__ bsum, int nb) {
    __shared__ int s[256];
    int t = threadIdx.x;
    int v = (t < nb) ? bsum[t] : 0;
    s[t] = v;
    __syncthreads();
#pragma unroll
    for (int d = 1; d < 256; d <<= 1) {
        int u = (t >= d) ? s[t - d] : 0;
        __syncthreads();
        s[t] += u;
        __syncthreads();
    }
    if (t < nb) bsum[t] = s[t] - v;   // exclusive block offsets, in place
}

__global__ void scan3_kernel(int* __restrict__ starts, const int* __restrict__ boff,
                             int n, int E) {
    int i = blockIdx.x * blockDim.x + threadIdx.x;
    if (i == 0) starts[n] = E;   // sentinel
    if (i < n) starts[i] += boff[blockIdx.x];
}

// ---------------------------------------------------------------- CSR scatter (atomic-free)
// pairs[pos] = {src (low32), norm (high32)} grouped by destination.
// 4 edges/thread for load-chain ILP.
__global__ void scatter2_kernel(const void* __restrict__ ei, const float* __restrict__ w,
                                const float* __restrict__ dinv, const int* __restrict__ starts,
                                const u32* __restrict__ rank, u64* __restrict__ pairs,
                                const int* __restrict__ flag, int E) {
    int i0 = (blockIdx.x * blockDim.x + threadIdx.x) * 4;
    if (i0 >= E) return;
    int f = *flag;
    int r[4], c[4];
#pragma unroll
    for (int k = 0; k < 4; k++) {
        int i = i0 + k;
        if (i < E) { r[k] = load_row(ei, i, E, f); c[k] = load_col(ei, i, E, f); }
    }
#pragma unroll
    for (int k = 0; k < 4; k++) {
        int i = i0 + k;
        if (i < E) {
            float nm = dinv[r[k]] * w[i] * dinv[c[k]];
            int pos = starts[c[k]] + (int)rank[i];
            pairs[pos] = ((u64)__float_as_uint(nm) << 32) | (u32)r[k];
        }
    }
}

// ---------------------------------------------------------------- fp32 -> bf16 convert
// xb = bf16(x) [N*128], hb = bf16(hidden) [N*64]
__global__ void cvt_kernel(const float* __restrict__ x, const float* __restrict__ hidden,
                           unsigned short* __restrict__ xb, unsigned short* __restrict__ hb,
                           int nx, int nh) {
    int i4 = (blockIdx.x * blockDim.x + threadIdx.x) * 4;
    if (i4 < nx) {
        float4 v = *(const float4*)&x[i4];
        ushort4 o = { f2bf(v.x), f2bf(v.y), f2bf(v.z), f2bf(v.w) };
        *(ushort4*)&xb[i4] = o;
    } else {
        int j = i4 - nx;
        if (j < nh) {
            float4 v = *(const float4*)&hidden[j];
            ushort4 o = { f2bf(v.x), f2bf(v.y), f2bf(v.z), f2bf(v.w) };
            *(ushort4*)&hb[j] = o;
        }
    }
}

// ---------------------------------------------------------------- weight pack (k-major bf16)
// Bzrt[col][k], col<64 from Wz[:,col], col in 64..127 from Wr[:,col-64]
// Wht[col][k]  = Wh[k][col]
__global__ void packW_kernel(const float* __restrict__ Wz, const float* __restrict__ Wr,
                             const float* __restrict__ Wh,
                             unsigned short* __restrict__ Bzrt, unsigned short* __restrict__ Wht) {
    int i = blockIdx.x * blockDim.x + threadIdx.x;
    if (i >= 192 * CAT_CH) return;
    int col = i / CAT_CH, k = i % CAT_CH;
    if (col < 128) {
        float v = (col < 64) ? Wz[k * 64 + col] : Wr[k * 64 + (col - 64)];
        Bzrt[col * CAT_CH + k] = f2bf(v);
    } else {
        Wht[(col - 128) * CAT_CH + k] = f2bf(Wh[k * 64 + (col - 128)]);
    }
}

// ---------------------------------------------------------------- bf16 MFMA GEMM
// C[M][TN] bf16 = [A0 | A1]([M][a0w] ++ [M][a1w], K=192 bf16) @ Bt([TN][192] bf16)
// 256 threads = 4 waves; block tile 128 rows; wave owns 32 rows x TN cols.
template <int TN>
__global__ __launch_bounds__(256) void gemm_bf16_kernel(
    const unsigned short* __restrict__ A0, int a0w,
    const unsigned short* __restrict__ A1, int a1w,
    const unsigned short* __restrict__ Bt,
    unsigned short* __restrict__ C, int nrows)
{
    __shared__ unsigned short As[128][48];    // 32 k + 16 pad
    __shared__ unsigned short Bs[TN][200];    // 192 k + 8 pad

    const int t = threadIdx.x, lane = t & 63, wave = t >> 6;
    const int rowBase = blockIdx.x * 128;

    // stage all of Bt once (16B chunks; 192 % 8 == 0 keeps chunks within a row)
    for (int idx = t * 8; idx < TN * CAT_CH; idx += 256 * 8) {
        int col = idx / CAT_CH, k = idx % CAT_CH;
        *(int4*)&Bs[col][k] = *(const int4*)&Bt[idx];
    }

    f32x4 acc[2][TN / 16];
#pragma unroll
    for (int rf = 0; rf < 2; rf++)
#pragma unroll
        for (int cf = 0; cf < TN / 16; cf++) acc[rf][cf] = (f32x4){0.f, 0.f, 0.f, 0.f};

    const int srow = t >> 1, half = t & 1;     // A staging: 2 threads/row, 32B each
    int arow = rowBase + srow;
    if (arow >= nrows) arow = nrows - 1;

    for (int k0 = 0; k0 < CAT_CH; k0 += 32) {
        __syncthreads();   // prev compute done (also orders first B stage)
        {
            const unsigned short* src = (k0 < a0w)
                ? A0 + (size_t)arow * a0w + k0
                : A1 + (size_t)arow * a1w + (k0 - a0w);
            *(int4*)&As[srow][half * 16] = *(const int4*)(src + half * 16);
            *(int4*)&As[srow][half * 16 + 8] = *(const int4*)(src + half * 16 + 8);
        }
        __syncthreads();

        const int rbase = wave * 32;
        const int koff = (lane >> 4) * 8;
        bf16x8 a0 = *(const bf16x8*)&As[rbase + (lane & 15)][koff];
        bf16x8 a1 = *(const bf16x8*)&As[rbase + 16 + (lane & 15)][koff];
#pragma unroll
        for (int cf = 0; cf < TN / 16; cf++) {
            bf16x8 b = *(const bf16x8*)&Bs[cf * 16 + (lane & 15)][k0 + koff];
            acc[0][cf] = __builtin_amdgcn_mfma_f32_16x16x32_bf16(a0, b, acc[0][cf], 0, 0, 0);
            acc[1][cf] = __builtin_amdgcn_mfma_f32_16x16x32_bf16(a1, b, acc[1][cf], 0, 0, 0);
        }
    }

#pragma unroll
    for (int rf = 0; rf < 2; rf++)
#pragma unroll
        for (int cf = 0; cf < TN / 16; cf++) {
            int row0 = rowBase + wave * 32 + rf * 16 + (lane >> 4) * 4;
            int col  = cf * 16 + (lane & 15);
#pragma unroll
            for (int r = 0; r < 4; r++) {
                int row = row0 + r;
                if (row < nrows) C[(size_t)row * TN + col] = f2bf(acc[rf][cf][r]);
            }
        }
}

// ---------------------------------------------------------------- SpMM (CSR gather, bf16 H)
// One wave per node, 128 ch of Hzrb (2 ch/lane), 8-deep pipelined gather,
// fused z/r epilogue.
__global__ __launch_bounds__(256) void spmm_zr_kernel(
    const unsigned short* __restrict__ H, const u64* __restrict__ pairs,
    const int* __restrict__ starts, const float* __restrict__ dinv,
    const float* __restrict__ hidden, const float* __restrict__ bz,
    const float* __restrict__ br, float* __restrict__ Z,
    unsigned short* __restrict__ RHb, int N)
{
    int node = (blockIdx.x * 256 + threadIdx.x) >> 6;
    if (node >= N) return;
    int lane = threadIdx.x & 63;
    int s = starts[node], e = starts[node + 1];
    float d = dinv[node], d2 = d * d;
    const int ch = lane * 2;

    u32 self = *(const u32*)&H[(size_t)node * 128 + ch];
    float ax = bflo(self) * d2, ay = bfhi(self) * d2;

    for (int j = s; j < e; j += 8) {
        u32 hv[8]; float nm[8];
#pragma unroll
        for (int k = 0; k < 8; k++) {
            int jj = j + k;
            u64 p = pairs[(jj < e) ? jj : (e - 1)];   // clamp dup -> L1 hit
            nm[k] = (jj < e) ? __uint_as_float((u32)(p >> 32)) : 0.f;
            hv[k] = *(const u32*)&H[(size_t)(u32)p * 128 + ch];
        }
#pragma unroll
        for (int k = 0; k < 8; k++) {
            ax = fmaf(bflo(hv[k]), nm[k], ax);
            ay = fmaf(bfhi(hv[k]), nm[k], ay);
        }
    }

    if (lane < 32) {
        int c = ch;                                 // z channels 0..62
        float2 o = { sigmoidf_(ax + bz[c]), sigmoidf_(ay + bz[c + 1]) };
        *(float2*)&Z[(size_t)node * 64 + c] = o;
    } else {
        int c = ch - 64;                            // r channels 0..62
        const float* hid = hidden + (size_t)node * 64 + c;
        float rh0 = sigmoidf_(ax + br[c])     * hid[0];
        float rh1 = sigmoidf_(ay + br[c + 1]) * hid[1];
        u32 packed = (u32)f2bf(rh0) | ((u32)f2bf(rh1) << 16);
        *(u32*)&RHb[(size_t)node * 64 + c] = packed;
    }
}

// One wave per node, 64 ch of Hhb, 8-deep pipelined gather,
// fused tanh + GRU blend -> out
__global__ __launch_bounds__(256) void spmm_h_kernel(
    const unsigned short* __restrict__ H, const u64* __restrict__ pairs,
    const int* __restrict__ starts, const float* __restrict__ dinv,
    const float* __restrict__ hidden, const float* __restrict__ bh,
    const float* __restrict__ Z, float* __restrict__ out, int N)
{
    int node = (blockIdx.x * 256 + threadIdx.x) >> 6;
    if (node >= N) return;
    int lane = threadIdx.x & 63;
    int s = starts[node], e = starts[node + 1];
    float d = dinv[node], d2 = d * d;

    float acc = bf1(H[(size_t)node * 64 + lane]) * d2;

    for (int j = s; j < e; j += 8) {
        unsigned short hv[8]; float nm[8];
#pragma unroll
        for (int k = 0; k < 8; k++) {
            int jj = j + k;
            u64 p = pairs[(jj < e) ? jj : (e - 1)];
            nm[k] = (jj < e) ? __uint_as_float((u32)(p >> 32)) : 0.f;
            hv[k] = H[(size_t)(u32)p * 64 + lane];
        }
#pragma unroll
        for (int k = 0; k < 8; k++)
            acc = fmaf(bf1(hv[k]), nm[k], acc);
    }

    size_t idx = (size_t)node * 64 + lane;
    float hc = tanhf(acc + bh[lane]);
    float z  = Z[idx];
    out[idx] = z * hidden[idx] + (1.f - z) * hc;
}

// ---------------------------------------------------------------- launcher
extern "C" void kernel_launch(void* const* d_in, const int* in_sizes, int n_in,
                              void* d_out, int out_size, void* d_ws, size_t ws_size,
                              hipStream_t stream) {
    const float* x      = (const float*)d_in[0];
    const void*  eidx   = d_in[1];
    const float* ew     = (const float*)d_in[2];
    const float* hidden = (const float*)d_in[3];
    const float* Wz     = (const float*)d_in[4];
    const float* bz     = (const float*)d_in[5];
    const float* Wr     = (const float*)d_in[6];
    const float* br     = (const float*)d_in[7];
    const float* Wh     = (const float*)d_in[8];
    const float* bh     = (const float*)d_in[9];
    float* out = (float*)d_out;

    const int E = in_sizes[2];            // 800000
    const int N = in_sizes[3] / OUT_CH;   // 50000

    // workspace carve-up (256B aligned)
    char* base = (char*)d_ws;
    size_t off = 0;
    auto carve = [&](size_t bytes) -> char* {
        char* p = base + off;
        off = (off + bytes + 255) & ~(size_t)255;
        return p;
    };
    u64*   packed = (u64*)  carve((size_t)N * 8);
    u32*   rank   = (u32*)  carve((size_t)E * 4);
    float* dinv   = (float*)carve((size_t)N * 4);
    int*   counts = (int*)  carve((size_t)N * 4);
    int*   starts = (int*)  carve((size_t)(N + 1) * 4);
    int*   bsum   = (int*)  carve(256 * 4);
    u64*   pairs  = (u64*)  carve((size_t)E * 8);
    unsigned short* xb   = (unsigned short*)carve((size_t)N * 128 * 2);
    unsigned short* hb   = (unsigned short*)carve((size_t)N * 64 * 2);
    unsigned short* Hzrb = (unsigned short*)carve((size_t)N * 128 * 2);
    unsigned short* RHb  = (unsigned short*)carve((size_t)N * 64 * 2);
    unsigned short* Hhb  = (unsigned short*)carve((size_t)N * 64 * 2);
    float* Z = (float*)carve((size_t)N * 64 * 4);
    unsigned short* Bzrt = (unsigned short*)carve((size_t)128 * CAT_CH * 2);
    unsigned short* Wht  = (unsigned short*)carve((size_t)64 * CAT_CH * 2);
    int* flag = (int*)carve(4);
    if (off > ws_size) return;

    const int B256 = 256;
    const int gE4 = (E + 1023) / 1024;        // 4 edges/thread kernels
    const int gN = (N + B256 - 1) / B256;     // scan blocking (<=256 blocks)
    const int gM = (N + 127) / 128;           // GEMM row tiles
    const int gW = (N + 3) / 4;               // one wave per node

    // 1. dtype detect
    hipLaunchKernelGGL(detect_kernel, dim3(1), dim3(64), 0, stream,
                       (const unsigned int*)eidx, flag);

    // 2. packed histogram (count | sum w) + per-edge rank
    hipMemsetAsync(packed, 0, (size_t)N * 8, stream);
    hipLaunchKernelGGL(hist2_kernel, dim3(gE4), dim3(B256), 0, stream,
                       eidx, ew, packed, rank, flag, E);
    hipLaunchKernelGGL(dinvc_kernel, dim3(gN), dim3(B256), 0, stream,
                       packed, dinv, counts, N);

    // 3. exclusive scan -> starts
    hipLaunchKernelGGL(scan1_kernel, dim3(gN), dim3(B256), 0, stream, counts, starts, bsum, N);
    hipLaunchKernelGGL(scan2_kernel, dim3(1), dim3(B256), 0, stream, bsum, gN);
    hipLaunchKernelGGL(scan3_kernel, dim3(gN), dim3(B256), 0, stream, starts, bsum, N, E);

    // 4. atomic-free CSR scatter
    hipLaunchKernelGGL(scatter2_kernel, dim3(gE4), dim3(B256), 0, stream,
                       eidx, ew, dinv, starts, rank, pairs, flag, E);

    // 5. bf16 conversions + weight packs
    hipLaunchKernelGGL(cvt_kernel, dim3((N * CAT_CH / 4 + 255) / 256), dim3(B256), 0, stream,
                       x, hidden, xb, hb, N * 128, N * 64);
    hipLaunchKernelGGL(packW_kernel, dim3((192 * CAT_CH + 255) / 256), dim3(B256), 0, stream,
                       Wz, Wr, Wh, Bzrt, Wht);

    // 6. GEMM1: Hzrb = [xb|hb] @ [Wz|Wr]   (bf16 MFMA)
    hipLaunchKernelGGL((gemm_bf16_kernel<128>), dim3(gM), dim3(B256), 0, stream,
                       xb, 128, hb, 64, Bzrt, Hzrb, N);

    // 7. z/r aggregation + sigmoid epilogue -> Z (fp32), RHb (bf16)
    hipLaunchKernelGGL(spmm_zr_kernel, dim3(gW), dim3(B256), 0, stream,
                       Hzrb, pairs, starts, dinv, hidden, bz, br, Z, RHb, N);

    // 8. GEMM2: Hhb = [xb|RHb] @ Wh   (single fused K=192 GEMM)
    hipLaunchKernelGGL((gemm_bf16_kernel<64>), dim3(gM), dim3(B256), 0, stream,
                       xb, 128, RHb, 64, Wht, Hhb, N);

    // 9. h-candidate aggregation + tanh/GRU blend -> out
    hipLaunchKernelGGL(spmm_h_kernel, dim3(gW), dim3(B256), 0, stream,
                       Hhb, pairs, starts, dinv, hidden, bh, Z, out, N);
}